// Round 1
// baseline (1788.444 us; speedup 1.0000x reference)
//
#include <hip/hip_runtime.h>
#include <hip/hip_cooperative_groups.h>
#include <cstdint>
#include <cstddef>

namespace cg = cooperative_groups;

// Problem dims (fixed). Inputs fp32, output fp32.
#define B_DIM 1024
#define T_DIM 32
#define V_DIM 1024
#define E_DIM 512
#define H_DIM 1024
#define O_DIM 1024

typedef unsigned short u16;
typedef __attribute__((ext_vector_type(8))) __bf16 bf16x8;  // MFMA A/B frag
typedef __attribute__((ext_vector_type(4))) float f32x4;    // MFMA C/D frag

__device__ __forceinline__ float bf2f(u16 u) {
  union { unsigned int i; float f; } v; v.i = ((unsigned int)u) << 16; return v.f;
}
__device__ __forceinline__ u16 f2bf(float f) {
  union { float f; unsigned int i; } v; v.f = f;
  return (u16)((v.i + 0x7fffu + ((v.i >> 16) & 1u)) >> 16);  // RNE
}
// async global->LDS, 16B/lane; HW writes lds_base + lane*16 (wave-uniform base)
__device__ __forceinline__ void async_cp16(const void* g, void* l) {
  __builtin_amdgcn_global_load_lds(
      (const __attribute__((address_space(1))) void*)g,
      (__attribute__((address_space(3))) void*)l, 16, 0, 0);
}
// fast tanh via hw exp+rcp: exact at +-inf, |err| ~1e-6 (<< bf16 ulp)
__device__ __forceinline__ float fast_tanh(float v) {
  return 1.f - 2.f / (__expf(2.f * v) + 1.f);
}

// ---------------------------------------------------------------------------
// Convert W_hh and W_out fp32 -> bf16 (1M elems each).
// ---------------------------------------------------------------------------
__global__ __launch_bounds__(256) void convert_w2(
    const float* __restrict__ a, const float* __restrict__ b,
    u16* __restrict__ da, u16* __restrict__ db) {
  const int nq = 1048576 / 4;
  int i = blockIdx.x * blockDim.x + threadIdx.x;
  const int stride = gridDim.x * blockDim.x;
  const float4* a4 = (const float4*)a;
  const float4* b4 = (const float4*)b;
  for (; i < nq; i += stride) {
    float4 va = a4[i], vb = b4[i];
    ushort4 oa = {f2bf(va.x), f2bf(va.y), f2bf(va.z), f2bf(va.w)};
    ushort4 ob = {f2bf(vb.x), f2bf(vb.y), f2bf(vb.z), f2bf(vb.w)};
    *(ushort4*)(da + 4 * (size_t)i) = oa;
    *(ushort4*)(db + 4 * (size_t)i) = ob;
  }
}

// ---------------------------------------------------------------------------
// W_comb[h][v] = sum_e W_ih[h][e] * W_emb[e][v]  (VALU, verified)
// ---------------------------------------------------------------------------
__global__ __launch_bounds__(256) void wcomb_valu(
    const float* __restrict__ Wih, const float* __restrict__ Wemb,
    u16* __restrict__ Wc) {
  __shared__ __align__(16) float As[16][68];
  __shared__ __align__(16) float Bs[16][68];
  const int tx = threadIdx.x & 15, ty = threadIdx.x >> 4;
  const int v0 = blockIdx.x * 64, h0 = blockIdx.y * 64;
  float acc[4][4] = {};
  for (int kt = 0; kt < 32; ++kt) {  // K = 512
#pragma unroll
    for (int i = 0; i < 4; ++i) {
      int idx = threadIdx.x + i * 256;
      int row = idx >> 4, k = idx & 15;
      As[k][row] = Wih[(size_t)(h0 + row) * E_DIM + kt * 16 + k];
      Bs[k][row] = Wemb[(size_t)(kt * 16 + k) * V_DIM + v0 + row];
    }
    __syncthreads();
    for (int k = 0; k < 16; ++k) {
      float4 a = *(const float4*)&As[k][ty * 4];
      float4 b = *(const float4*)&Bs[k][tx * 4];
      const float av[4] = {a.x, a.y, a.z, a.w}, bv[4] = {b.x, b.y, b.z, b.w};
#pragma unroll
      for (int i = 0; i < 4; ++i)
#pragma unroll
        for (int j = 0; j < 4; ++j) acc[i][j] += av[i] * bv[j];
    }
    __syncthreads();
  }
#pragma unroll
  for (int i = 0; i < 4; ++i)
#pragma unroll
    for (int j = 0; j < 4; ++j)
      Wc[(size_t)(h0 + ty * 4 + i) * V_DIM + v0 + tx * 4 + j] = f2bf(acc[i][j]);
}

// b_comb[h] = W_ih[h,:].b_emb + b_ih[h]  (all fp32)
__global__ __launch_bounds__(256) void bcomb_valu(
    const float* __restrict__ Wih, const float* __restrict__ bemb,
    const float* __restrict__ bih, float* __restrict__ bc) {
  int h = blockIdx.x * 256 + threadIdx.x;  // grid 4
  float s = 0.f;
  for (int e = 0; e < E_DIM; ++e) s += Wih[(size_t)h * E_DIM + e] * bemb[e];
  bc[h] = s + bih[h];
}

// ---------------------------------------------------------------------------
// x_proj [T,B,H] bf16: xp[t][b][h] = msg[b*32+t][:] . Wc[h][:] + bc[h]
// 128x128 MFMA tile. T2 XOR-swizzle on As/Bs (was a 16-way conflict @128B
// stride, 23% of cycles): col_elem ^= (row&7)<<3. Bs is staged via
// global_load_lds -> swizzle applied on the per-lane GLOBAL source (rule #21);
// As is ds_write from regs -> swizzle on the write address. Reads swizzled.
// ---------------------------------------------------------------------------
__global__ __launch_bounds__(256) void xproj_mfma(
    const float* __restrict__ msg, const u16* __restrict__ Wc,
    const float* __restrict__ bc, u16* __restrict__ xp) {
  __shared__ u16 As[128 * 64];
  __shared__ u16 Bs[128 * 64];
  const int tid = threadIdx.x, lane = tid & 63, w = tid >> 6;
  const int lrow = lane >> 4, lcol = lane & 15;
  const int n0 = blockIdx.x * 128, m0 = blockIdx.y * 128;
  const int mq = (w & 1) * 64, nq = (w >> 1) * 64;
  f32x4 acc[4][4] = {};
  const int r8 = lane >> 3, l7 = lane & 7;
  const int ar = tid >> 1, ak = (tid & 1) * 32;

  auto stageB = [&](int kk) {
#pragma unroll
    for (int i = 0; i < 4; ++i) {
      int ch = w * 4 + i;
      // source col pre-swizzled: slot (row, l7*8) holds logical col (l7^r8)*8
      async_cp16(Wc + (size_t)(n0 + ch * 8 + r8) * V_DIM + kk * 64 + ((l7 ^ r8) << 3),
                 Bs + ch * 512);
    }
  };
  float4 areg[8];
  auto loadA = [&](int kk) {
    const float4* src = (const float4*)(msg + (size_t)(m0 + ar) * V_DIM + kk * 64 + ak);
#pragma unroll
    for (int i = 0; i < 8; ++i) areg[i] = src[i];
  };
  auto writeA = [&]() {
    u16 tmp[32];
#pragma unroll
    for (int i = 0; i < 8; ++i) {
      tmp[i * 4 + 0] = f2bf(areg[i].x);
      tmp[i * 4 + 1] = f2bf(areg[i].y);
      tmp[i * 4 + 2] = f2bf(areg[i].z);
      tmp[i * 4 + 3] = f2bf(areg[i].w);
    }
#pragma unroll
    for (int i = 0; i < 4; ++i) {
      int c = (ak + i * 8) ^ ((ar & 7) << 3);  // swizzled write
      *(uint4*)(As + (size_t)ar * 64 + c) = *(const uint4*)(tmp + i * 8);
    }
  };

  loadA(0);
  stageB(0);
  writeA();
  for (int kk = 0; kk < 16; ++kk) {
    __syncthreads();
    if (kk < 15) loadA(kk + 1);
#pragma unroll
    for (int ks = 0; ks < 2; ++ks) {
      const int kb = ks * 32 + lrow * 8;
      bf16x8 a[4], b[4];
#pragma unroll
      for (int mt = 0; mt < 4; ++mt) {
        int row = mq + mt * 16 + lcol;
        a[mt] = *(const bf16x8*)(As + row * 64 + (kb ^ ((row & 7) << 3)));
      }
#pragma unroll
      for (int nt = 0; nt < 4; ++nt) {
        int row = nq + nt * 16 + lcol;
        b[nt] = *(const bf16x8*)(Bs + row * 64 + (kb ^ ((row & 7) << 3)));
      }
#pragma unroll
      for (int mt = 0; mt < 4; ++mt)
#pragma unroll
        for (int nt = 0; nt < 4; ++nt)
          acc[mt][nt] = __builtin_amdgcn_mfma_f32_16x16x32_bf16(a[mt], b[nt], acc[mt][nt], 0, 0, 0);
    }
    __syncthreads();
    if (kk < 15) { stageB(kk + 1); writeA(); }
  }
  float bcv[4];
#pragma unroll
  for (int nt = 0; nt < 4; ++nt) bcv[nt] = bc[n0 + nq + nt * 16 + lcol];
#pragma unroll
  for (int mt = 0; mt < 4; ++mt)
#pragma unroll
    for (int rr = 0; rr < 4; ++rr) {
      int rg = m0 + mq + mt * 16 + lrow * 4 + rr;  // flat (b*T + t)
      int bI = rg >> 5, tI = rg & 31;
      u16* dst = xp + ((size_t)tI * B_DIM + bI) * H_DIM + n0 + nq;
#pragma unroll
      for (int nt = 0; nt < 4; ++nt)
        dst[nt * 16 + lcol] = f2bf(acc[mt][nt][rr] + bcv[nt]);
    }
}

// ---------------------------------------------------------------------------
// Persistent cooperative RNN: all 32 steps + output GEMM in ONE dispatch.
// Grid 256 blocks (1/CU), 256 threads. Each block owns a 64x64 output tile
// (n0 = (bid&15)*64, m0 = (bid>>4)*64).
//  - W slice [64 rows n0..][K=1024] bf16 = 128 KB resident in LDS all steps
//    (staged once via global_load_lds, XOR-swizzled through the source addr).
//  - A (h_prev) chunks 64x64 double-buffered, staged 2 chunks deep with
//    counted s_waitcnt vmcnt(2) + raw s_barrier (never drain to 0 mid-loop).
//  - x_t prefetched into regs at step start (issued BEFORE the stage loads so
//    the vmcnt count stays sound: stages only ever get OLDER, never newer).
//  - grid.sync() once per step (release/acquire handles cross-XCD L2).
// LDS: 131072 (W) + 2*8192 (A dbuf) = 147456 B -> 1 block/CU.
// ---------------------------------------------------------------------------
__global__ __launch_bounds__(256, 1) void rnn_fused(
    const u16* __restrict__ Whh_b, const u16* __restrict__ Wout_b,
    const u16* __restrict__ xp, const float* __restrict__ bhh,
    const float* __restrict__ bout, u16* __restrict__ hA,
    u16* __restrict__ hB, float* __restrict__ outp) {
  __shared__ __align__(16) u16 Wlds[64 * 1024];   // 128 KB
  __shared__ __align__(16) u16 Abuf[2][64 * 64];  // 2 x 8 KB
  cg::grid_group grid = cg::this_grid();

  const int tid = threadIdx.x, lane = tid & 63, w = tid >> 6;
  const int lrow = lane >> 4, lcol = lane & 15;
  const int l7 = lane & 7, r8 = lane >> 3;
  const int bid = blockIdx.x;
  const int n0 = (bid & 15) * 64, m0 = (bid >> 4) * 64;
  const int mq = (w & 1) * 32, nq = (w >> 1) * 32;

  // Stage a 64x1024 W slice into Wlds, swizzled. 32 passes x 4 KB.
  // pass pp: LDS byte L = pp*4096 + w*1024 + lane*16 -> row r = pp*2 + (w>>1),
  // phys col byte cbp = (w&1)*1024 + lane*16; source col = cbp ^ ((r&7)<<4).
  auto stageW = [&](const u16* Wsrc) {
#pragma unroll 4
    for (int pp = 0; pp < 32; ++pp) {
      int r = pp * 2 + (w >> 1);
      int cb = ((w & 1) * 1024 + lane * 16) ^ ((r & 7) << 4);
      async_cp16(Wsrc + (size_t)(n0 + r) * H_DIM + (cb >> 1),
                 Wlds + pp * 2048 + w * 512);
    }
  };
  // Stage one 64x64 A chunk (rows m0.., cols kk*64..) into buf, swizzled.
  // pass p: row r = p*32 + w*8 + r8 (r&7==r8), src col elems = (l7^r8)*8.
  auto stageA = [&](const u16* hin, int kk, u16* buf) {
#pragma unroll
    for (int p = 0; p < 2; ++p) {
      int r = p * 32 + w * 8 + r8;
      async_cp16(hin + (size_t)(m0 + r) * H_DIM + kk * 64 + ((l7 ^ r8) << 3),
                 buf + p * 2048 + w * 512);
    }
  };

  // per-lane fragment row constants (swizzle shift is row&7 << 3 in elems)
  const int rA0 = mq + lcol, rA1 = mq + 16 + lcol;
  const int rB0 = nq + lcol, rB1 = nq + 16 + lcol;
  const int sA0 = (rA0 & 7) << 3, sA1 = (rA1 & 7) << 3;
  const int sB0 = (rB0 & 7) << 3, sB1 = (rB1 & 7) << 3;

  f32x4 acc[2][2];
  auto kchunk = [&](const u16* Ab, int kk) {
#pragma unroll
    for (int ks = 0; ks < 2; ++ks) {
      const int ca = ks * 32 + lrow * 8;
      const int cw = kk * 64 + ks * 32 + lrow * 8;
      bf16x8 a0 = *(const bf16x8*)(Ab + rA0 * 64 + (ca ^ sA0));
      bf16x8 a1 = *(const bf16x8*)(Ab + rA1 * 64 + (ca ^ sA1));
      bf16x8 b0 = *(const bf16x8*)(Wlds + rB0 * 1024 + (cw ^ sB0));
      bf16x8 b1 = *(const bf16x8*)(Wlds + rB1 * 1024 + (cw ^ sB1));
      acc[0][0] = __builtin_amdgcn_mfma_f32_16x16x32_bf16(a0, b0, acc[0][0], 0, 0, 0);
      acc[0][1] = __builtin_amdgcn_mfma_f32_16x16x32_bf16(a0, b1, acc[0][1], 0, 0, 0);
      acc[1][0] = __builtin_amdgcn_mfma_f32_16x16x32_bf16(a1, b0, acc[1][0], 0, 0, 0);
      acc[1][1] = __builtin_amdgcn_mfma_f32_16x16x32_bf16(a1, b1, acc[1][1], 0, 0, 0);
    }
  };
  // K-loop: counted vmcnt keeps 1 chunk prefetched across the barrier.
  auto kloop = [&](const u16* hin) {
    stageA(hin, 0, Abuf[0]);
    stageA(hin, 1, Abuf[1]);
    for (int kk = 0; kk < 16; ++kk) {
      if (kk < 15) asm volatile("s_waitcnt vmcnt(2)" ::: "memory");
      else         asm volatile("s_waitcnt vmcnt(0)" ::: "memory");
      __builtin_amdgcn_s_barrier();               // chunk kk visible to all
      const u16* Ab = (kk & 1) ? Abuf[1] : Abuf[0];
      kchunk(Ab, kk);
      __builtin_amdgcn_s_barrier();               // all reads of buf done
      if (kk < 14) stageA(hin, kk + 2, (kk & 1) ? Abuf[1] : Abuf[0]);
    }
  };

  stageW(Whh_b);  // drained by t=1's vmcnt chain; visible after t=0 grid.sync
  const float bv0 = bhh[n0 + nq + lcol], bv1 = bhh[n0 + nq + 16 + lcol];
  u16* houts[2] = {hA, hB};

  for (int t = 0; t < T_DIM; ++t) {
    // prefetch x_t epilogue values (issued before this step's stage loads)
    const u16* xrow = xp + (size_t)t * (B_DIM * H_DIM);
    u16 xv[2][2][4];
#pragma unroll
    for (int mt = 0; mt < 2; ++mt)
#pragma unroll
      for (int rr = 0; rr < 4; ++rr) {
        int row = m0 + mq + mt * 16 + lrow * 4 + rr;
#pragma unroll
        for (int nt = 0; nt < 2; ++nt)
          xv[mt][nt][rr] = xrow[(size_t)row * H_DIM + n0 + nq + nt * 16 + lcol];
      }
#pragma unroll
    for (int i = 0; i < 2; ++i)
#pragma unroll
      for (int j = 0; j < 2; ++j) acc[i][j] = (f32x4){0.f, 0.f, 0.f, 0.f};
    if (t > 0) kloop(houts[(t & 1) ^ 1]);
    u16* hout = houts[t & 1];
#pragma unroll
    for (int mt = 0; mt < 2; ++mt)
#pragma unroll
      for (int rr = 0; rr < 4; ++rr) {
        int row = m0 + mq + mt * 16 + lrow * 4 + rr;
#pragma unroll
        for (int nt = 0; nt < 2; ++nt) {
          int col = n0 + nq + nt * 16 + lcol;
          float v = acc[mt][nt][rr] + (nt ? bv1 : bv0) + bf2f(xv[mt][nt][rr]);
          hout[(size_t)row * H_DIM + col] = f2bf(fast_tanh(v));
        }
      }
    grid.sync();  // h(t) visible device-wide; also block-local barrier
  }

  // ---- output GEMM: out = h31 . W_out^T + b_out (fp32) ----
  const float bo0 = bout[n0 + nq + lcol], bo1 = bout[n0 + nq + 16 + lcol];
#pragma unroll
  for (int i = 0; i < 2; ++i)
#pragma unroll
    for (int j = 0; j < 2; ++j) acc[i][j] = (f32x4){0.f, 0.f, 0.f, 0.f};
  stageW(Wout_b);     // 32 loads, oldest in queue -> drained by kk=0's vmcnt(2)
  kloop(houts[1]);    // h after t=31 lives in hB
#pragma unroll
  for (int mt = 0; mt < 2; ++mt)
#pragma unroll
    for (int rr = 0; rr < 4; ++rr) {
      int row = m0 + mq + mt * 16 + lrow * 4 + rr;
#pragma unroll
      for (int nt = 0; nt < 2; ++nt) {
        int col = n0 + nq + nt * 16 + lcol;
        outp[(size_t)row * O_DIM + col] = acc[mt][nt][rr] + (nt ? bo1 : bo0);
      }
    }
}

// ---------------------------------------------------------------------------
extern "C" void kernel_launch(void* const* d_in, const int* in_sizes, int n_in,
                              void* d_out, int out_size, void* d_ws, size_t ws_size,
                              hipStream_t stream) {
  const float* msg  = (const float*)d_in[0];
  const float* Wemb = (const float*)d_in[1];
  const float* bemb = (const float*)d_in[2];
  const float* Wih  = (const float*)d_in[3];
  const float* bih  = (const float*)d_in[4];
  const float* Whh  = (const float*)d_in[5];
  const float* bhh  = (const float*)d_in[6];
  const float* Wout = (const float*)d_in[7];
  const float* bout = (const float*)d_in[8];
  char* ws = (char*)d_ws;

  // ws layout (bytes), total ~74 MB
  float* bc   = (float*)ws;               // 4096
  u16* Wc     = (u16*)(ws + 4096);        // 2 MB
  u16* Whh_b  = (u16*)(ws + 2101248);     // 2 MB
  u16* Wout_b = (u16*)(ws + 4198400);     // 2 MB
  u16* hA     = (u16*)(ws + 6295552);     // 2 MB
  u16* hB     = (u16*)(ws + 8392704);     // 2 MB
  u16* xp     = (u16*)(ws + 10489856);    // 64 MB
  const size_t NEED = 10489856 + 67108864;
  if (ws_size < NEED) return;

  convert_w2<<<512, 256, 0, stream>>>(Whh, Wout, Whh_b, Wout_b);
  wcomb_valu<<<dim3(16, 16), 256, 0, stream>>>(Wih, Wemb, Wc);
  bcomb_valu<<<4, 256, 0, stream>>>(Wih, bemb, bih, bc);
  xproj_mfma<<<dim3(8, 256), 256, 0, stream>>>(msg, Wc, bc, xp);

  // persistent cooperative kernel: 32 RNN steps + output GEMM
  const u16* a_whh = Whh_b; const u16* a_wout = Wout_b; const u16* a_xp = xp;
  const float* a_bhh = bhh; const float* a_bout = bout;
  u16* a_hA = hA; u16* a_hB = hB; float* a_out = (float*)d_out;
  void* kargs[] = {(void*)&a_whh, (void*)&a_wout, (void*)&a_xp,
                   (void*)&a_bhh, (void*)&a_bout, (void*)&a_hA,
                   (void*)&a_hB,  (void*)&a_out};
  hipLaunchCooperativeKernel((const void*)rnn_fused, dim3(256), dim3(256),
                             kargs, 0, stream);
}